// Round 8
// baseline (125.586 us; speedup 1.0000x reference)
//
#include <hip/hip_runtime.h>
#include <math.h>

// TopKMoEGate: T = 16384, D = 1024, E = 64, topK = 2.
// Round 8: r7's one-barrier MFMA structure + 2 m-tiles per wave.
//  - r7 pipe model: B LDS reads were the top pipe (96 b128/wave, 15.4 us/CU
//    aggregate) because a wave covered only 16 tokens. Now each wave covers
//    32 tokens (2 m-tiles), so each B frag feeds 12 MFMAs -> LDS traffic
//    per token halves (7.7 us/CU), below the HBM floor (~10.6 us).
//  - Block = 128 tokens x K=128 (NSPLIT=8): 1024 blocks, 48 KB LDS,
//    3 blocks/CU resident (launch_bounds(256,3)), 12 waves/CU.
//  - All fragment layouts identical to r4/r5/r7 (verified): 16x16x32 bf16,
//    A m=lane&15 k=q*8+j, C row=q*4+r col=m; wimg lane-ordered image.
//  - 3-slice bf16 split (6 cross terms), fp32 partials, r3-verified
//    reduce+top-2+softmax kernel.

#define DDIM 1024
#define NEXP 64
#define NTOK 16384
#define NSPLIT 8
#define CPB 2                 // k64-chunks per block (K range 128)
#define CHUNK_SH 12288        // shorts per k64 chunk (1536 units * 8)

typedef float f4 __attribute__((ext_vector_type(4)));
typedef short s8 __attribute__((ext_vector_type(8)));
typedef unsigned int u32;

static __device__ __forceinline__ void split3(float f, short& h, short& m, short& l) {
    const u32 uf = __float_as_uint(f);
    h = (short)(uf >> 16);
    const float r1 = f - __uint_as_float(uf & 0xffff0000u);
    const u32 u1 = __float_as_uint(r1);
    m = (short)(u1 >> 16);
    const float r2 = r1 - __uint_as_float(u1 & 0xffff0000u);
    l = (short)(__float_as_uint(r2) >> 16);
}

static __device__ __forceinline__ void gl_lds16(const void* g, void* l) {
    __builtin_amdgcn_global_load_lds(
        (const __attribute__((address_space(1))) u32*)g,
        (__attribute__((address_space(3))) u32*)l, 16, 0, 0);
}

// ---- kernel 0: slice gate_w into 3 bf16 levels, lane-ordered image ----
// unit16 U(c,kk,lv,t,q,m) = c*1536 + (kk*3+lv)*256 + t*64 + q*16 + m,
// holding w[e=t*16+m][k0..k0+7], k0 = c*64 + kk*32 + q*8.  (r5-verified)
__global__ __launch_bounds__(256)
void w_prep(const float* __restrict__ gw, short* __restrict__ wimg) {
    const int uid = blockIdx.x * 256 + threadIdx.x;   // 8192 threads
    const int c   = uid >> 9;
    const int kk  = (uid >> 8) & 1;
    const int e   = (uid >> 2) & 63;
    const int q   = uid & 3;
    const int k0  = c * 64 + kk * 32 + q * 8;
    const float* src = gw + (size_t)e * DDIM + k0;
    s8 hv, mv, lv;
    #pragma unroll
    for (int j = 0; j < 8; ++j) {
        short h, m, l;
        split3(src[j], h, m, l);
        hv[j] = h; mv[j] = m; lv[j] = l;
    }
    const size_t base = (size_t)c * 1536 + (kk * 3) * 256
                      + (e >> 4) * 64 + q * 16 + (e & 15);
    *(s8*)(wimg + (base      ) * 8) = hv;
    *(s8*)(wimg + (base + 256) * 8) = mv;
    *(s8*)(wimg + (base + 512) * 8) = lv;
}

// ---- kernel 1: split-K MFMA GEMM, 2 m-tiles/wave -> fp32 partials ----
__global__ __launch_bounds__(256, 3)
void gemm_partial(const float* __restrict__ x,
                  const short* __restrict__ wimg,
                  float* __restrict__ part)     // [NSPLIT][NTOK][NEXP]
{
    __shared__ short bs[CPB * CHUNK_SH];        // 48 KB: block's B-slice

    const int tid   = threadIdx.x;
    const int lane  = tid & 63;
    const int wv    = tid >> 6;
    const int m     = lane & 15;                // A-frag row index
    const int q     = lane >> 4;                // k-octet quad
    const int tile  = blockIdx.x & 127;         // 128 token tiles
    const int split = blockIdx.x >> 7;
    const int tokBase = tile * 128 + wv * 32;   // wave covers 32 tokens

    // B staging: async direct-to-LDS, issued first; ONE barrier total.
    const short* bsrc = wimg + (size_t)(split * CPB) * CHUNK_SH;
    #pragma unroll
    for (int i = 0; i < 12; ++i) {
        const int off = (wv * 12 + i) * 512;    // 1 KB per wave-iter
        gl_lds16(bsrc + off + lane * 8, &bs[off]);
    }

    // two A row pointers (m-tile 0: rows 0..15, m-tile 1: rows 16..31)
    const float* xr0 = x + (size_t)(tokBase + m) * DDIM + split * (CPB * 64) + q * 8;
    const float* xr1 = xr0 + 16 * DDIM;

    // chunk-0 A loads in flight alongside B staging
    f4 stage[2][4];
    stage[0][0] = *(const f4*)(xr0);
    stage[0][1] = *(const f4*)(xr0 + 4);
    stage[0][2] = *(const f4*)(xr0 + 32);
    stage[0][3] = *(const f4*)(xr0 + 36);
    stage[1][0] = *(const f4*)(xr1);
    stage[1][1] = *(const f4*)(xr1 + 4);
    stage[1][2] = *(const f4*)(xr1 + 32);
    stage[1][3] = *(const f4*)(xr1 + 36);

    f4 acc0[2][4], acc1[2][4];
    #pragma unroll
    for (int mt = 0; mt < 2; ++mt)
        #pragma unroll
        for (int t = 0; t < 4; ++t) { acc0[mt][t] = (f4)0.f; acc1[mt][t] = (f4)0.f; }

    __syncthreads();                            // B visible; chunk-0 A in regs

    #pragma unroll
    for (int cc = 0; cc < CPB; ++cc) {
        // convert current chunk A (both m-tiles) -> 3-level bf16 frags
        s8 ah[2][2], am[2][2], al[2][2];        // [mt][kk]
        #pragma unroll
        for (int mt = 0; mt < 2; ++mt) {
            const float* sv = (const float*)&stage[mt][0];
            #pragma unroll
            for (int kk = 0; kk < 2; ++kk)
                #pragma unroll
                for (int j = 0; j < 8; ++j) {
                    short h, mm, l;
                    split3(sv[kk * 8 + j], h, mm, l);
                    ah[mt][kk][j] = h; am[mt][kk][j] = mm; al[mt][kk][j] = l;
                }
        }
        // prefetch next chunk A (latency covered by this chunk's MFMAs)
        if (cc + 1 < CPB) {
            stage[0][0] = *(const f4*)(xr0 + 64);
            stage[0][1] = *(const f4*)(xr0 + 68);
            stage[0][2] = *(const f4*)(xr0 + 96);
            stage[0][3] = *(const f4*)(xr0 + 100);
            stage[1][0] = *(const f4*)(xr1 + 64);
            stage[1][1] = *(const f4*)(xr1 + 68);
            stage[1][2] = *(const f4*)(xr1 + 96);
            stage[1][3] = *(const f4*)(xr1 + 100);
        }

        #pragma unroll
        for (int kk = 0; kk < 2; ++kk) {
            #pragma unroll
            for (int t = 0; t < 4; ++t) {
                const int pb = cc * 1536 + (kk * 3) * 256 + t * 64 + lane;
                const s8 bh = *(const s8*)&bs[(size_t)(pb      ) * 8];
                const s8 bm = *(const s8*)&bs[(size_t)(pb + 256) * 8];
                const s8 bl = *(const s8*)&bs[(size_t)(pb + 512) * 8];
                #pragma unroll
                for (int mt = 0; mt < 2; ++mt) {
                    acc0[mt][t] = __builtin_amdgcn_mfma_f32_16x16x32_bf16(ah[mt][kk], bh, acc0[mt][t], 0, 0, 0);
                    acc1[mt][t] = __builtin_amdgcn_mfma_f32_16x16x32_bf16(ah[mt][kk], bm, acc1[mt][t], 0, 0, 0);
                    acc1[mt][t] = __builtin_amdgcn_mfma_f32_16x16x32_bf16(am[mt][kk], bh, acc1[mt][t], 0, 0, 0);
                    acc1[mt][t] = __builtin_amdgcn_mfma_f32_16x16x32_bf16(ah[mt][kk], bl, acc1[mt][t], 0, 0, 0);
                    acc1[mt][t] = __builtin_amdgcn_mfma_f32_16x16x32_bf16(am[mt][kk], bm, acc1[mt][t], 0, 0, 0);
                    acc1[mt][t] = __builtin_amdgcn_mfma_f32_16x16x32_bf16(al[mt][kk], bh, acc1[mt][t], 0, 0, 0);
                }
            }
        }
    }

    // store partials: C row = q*4+r (token), col = m (+16t experts)
    #pragma unroll
    for (int mt = 0; mt < 2; ++mt)
        #pragma unroll
        for (int t = 0; t < 4; ++t)
            #pragma unroll
            for (int r = 0; r < 4; ++r)
                part[((size_t)split * NTOK + tokBase + mt * 16 + q * 4 + r) * NEXP + m + 16 * t]
                    = acc0[mt][t][r] + acc1[mt][t][r];
}

// ---- kernel 2: reduce splits + noisy top-2 + sparse softmax (r3-verified) ----
__global__ __launch_bounds__(256)
void reduce_topk(const float* __restrict__ part,
                 const float* __restrict__ noise_weight,
                 const float* __restrict__ noise,
                 float* __restrict__ out_w,
                 float* __restrict__ out_i)
{
    const int lane  = threadIdx.x & 63;          // expert
    const int wv    = threadIdx.x >> 6;
    const int token = blockIdx.x * 4 + wv;

    float sum = 0.f;
    #pragma unroll
    for (int s = 0; s < NSPLIT; ++s)
        sum += part[((size_t)s * NTOK + token) * NEXP + lane];

    const float ln = fmaf(noise[(size_t)token * NEXP + lane], noise_weight[lane], sum);

    float v1 = ln; int i1 = lane;
    #pragma unroll
    for (int off = 32; off > 0; off >>= 1) {
        const float vo = __shfl_xor(v1, off, 64);
        const int   io = __shfl_xor(i1, off, 64);
        if (vo > v1 || (vo == v1 && io < i1)) { v1 = vo; i1 = io; }
    }
    float v2 = (lane == i1) ? -3.4e38f : ln; int i2 = lane;
    #pragma unroll
    for (int off = 32; off > 0; off >>= 1) {
        const float vo = __shfl_xor(v2, off, 64);
        const int   io = __shfl_xor(i2, off, 64);
        if (vo > v2 || (vo == v2 && io < i2)) { v2 = vo; i2 = io; }
    }

    const float d   = expf(v2 - v1);
    const float inv = 1.f / (1.f + d);
    const float wgt = (lane == i1) ? inv : ((lane == i2) ? d * inv : 0.f);
    out_w[(size_t)token * NEXP + lane] = wgt;
    if (lane == 0) {
        out_i[(size_t)token * 2]     = (float)i1;
        out_i[(size_t)token * 2 + 1] = (float)i2;
    }
}

extern "C" void kernel_launch(void* const* d_in, const int* in_sizes, int n_in,
                              void* d_out, int out_size, void* d_ws, size_t ws_size,
                              hipStream_t stream) {
    const float* x     = (const float*)d_in[0];
    const float* gw    = (const float*)d_in[1];
    const float* nwt   = (const float*)d_in[2];
    const float* noise = (const float*)d_in[3];
    float* out_w = (float*)d_out;                        // [NTOK][64]
    float* out_i = (float*)d_out + (size_t)NTOK * NEXP;  // [NTOK][2] as float

    short* wimg = (short*)d_ws;                          // 384 KB image
    float* part = (float*)((char*)d_ws + 512 * 1024);    // 32 MB partials

    hipLaunchKernelGGL(w_prep, dim3(32), dim3(256), 0, stream, gw, wimg);
    hipLaunchKernelGGL(gemm_partial, dim3(128 * NSPLIT), dim3(256), 0, stream,
                       x, wimg, part);
    hipLaunchKernelGGL(reduce_topk, dim3(NTOK / 4), dim3(256), 0, stream,
                       part, nwt, noise, out_w, out_i);
}

// Round 9
// 125.149 us; speedup vs baseline: 1.0035x; 1.0035x over previous
//
#include <hip/hip_runtime.h>
#include <math.h>

// TopKMoEGate: T = 16384, D = 1024, E = 64, topK = 2.
// Round 9: FULLY FUSED. Intra-block split-K replaces grid split-K:
//  - r8 lesson: the gemm's pipes were not saturated; the controllable cost
//    was dominated by the 32 MB partial write + 40 MB read + reduce kernel.
//  - Block = 16 tokens x 4 waves; wave w computes K-quarter w (4 k64-chunks)
//    for the SAME 16 tokens. Partials exchanged via 16 KB LDS, ONE barrier,
//    fused r3-verified butterfly top-2 + sparse softmax epilogue.
//  - B direct from L2-resident pre-permuted wimg, 12 frags (48 VGPRs)
//    batched in flight per kk (r4's serial-chain failure was its 68-VGPR
//    budget; launch_bounds(256,3) allows ~170).
//  - Grid 1024 blocks -> 3-4 blocks/CU, 12+ waves/CU; no partials, no
//    reduce kernel, no global round-trip.
//  - 3-slice bf16 split (r4..r8-verified numerics).

#define DDIM 1024
#define NEXP 64
#define NTOK 16384
#define CPW 4                 // k64-chunks per wave (K-quarter = 256)
#define CHUNK_SH 12288        // shorts per k64 chunk (1536 units * 8)

typedef float f4 __attribute__((ext_vector_type(4)));
typedef short s8 __attribute__((ext_vector_type(8)));
typedef unsigned int u32;

static __device__ __forceinline__ void split3(float f, short& h, short& m, short& l) {
    const u32 uf = __float_as_uint(f);
    h = (short)(uf >> 16);
    const float r1 = f - __uint_as_float(uf & 0xffff0000u);
    const u32 u1 = __float_as_uint(r1);
    m = (short)(u1 >> 16);
    const float r2 = r1 - __uint_as_float(u1 & 0xffff0000u);
    l = (short)(__float_as_uint(r2) >> 16);
}

// ---- kernel 0: slice gate_w into 3 bf16 levels, lane-ordered image ----
// unit16 U(c,kk,lv,t,q,m) = c*1536 + (kk*3+lv)*256 + t*64 + (q*16+m),
// holding w[e=t*16+m][k0..k0+7], k0 = c*64 + kk*32 + q*8.  (r5-verified)
__global__ __launch_bounds__(256)
void w_prep(const float* __restrict__ gw, short* __restrict__ wimg) {
    const int uid = blockIdx.x * 256 + threadIdx.x;   // 8192 threads
    const int c   = uid >> 9;
    const int kk  = (uid >> 8) & 1;
    const int e   = (uid >> 2) & 63;
    const int q   = uid & 3;
    const int k0  = c * 64 + kk * 32 + q * 8;
    const float* src = gw + (size_t)e * DDIM + k0;
    s8 hv, mv, lv;
    #pragma unroll
    for (int j = 0; j < 8; ++j) {
        short h, m, l;
        split3(src[j], h, m, l);
        hv[j] = h; mv[j] = m; lv[j] = l;
    }
    const size_t base = (size_t)c * 1536 + (kk * 3) * 256
                      + (e >> 4) * 64 + q * 16 + (e & 15);
    *(s8*)(wimg + (base      ) * 8) = hv;
    *(s8*)(wimg + (base + 256) * 8) = mv;
    *(s8*)(wimg + (base + 512) * 8) = lv;
}

// ---- kernel 1: fused GEMM + block reduce + noisy top-2 + softmax ----
static __device__ __forceinline__ bool bt(float av, int ai, float bv, int bi) {
    return av > bv || (av == bv && ai < bi);   // jax.lax.top_k order
}

__global__ __launch_bounds__(256, 3)
void moe_fused(const float* __restrict__ x,
               const short* __restrict__ wimg,
               const float* __restrict__ nwt,
               const float* __restrict__ noise,
               float* __restrict__ out_w,
               float* __restrict__ out_i)
{
    __shared__ float red[4][16][NEXP];          // 16 KB partial exchange

    const int tid  = threadIdx.x;
    const int lane = tid & 63;
    const int wv   = tid >> 6;                  // K-quarter index
    const int m    = lane & 15;                 // A-frag row / C col
    const int q    = lane >> 4;                 // k-octet quad / C row-quad
    const int tokBase = blockIdx.x * 16;

    const float* xrow = x + (size_t)(tokBase + m) * DDIM + wv * (CPW * 64) + q * 8;

    f4 acc0[4], acc1[4];
    #pragma unroll
    for (int t = 0; t < 4; ++t) { acc0[t] = (f4)0.f; acc1[t] = (f4)0.f; }

    // A chunk-0 loads in flight immediately
    f4 As[4];
    As[0] = *(const f4*)(xrow);
    As[1] = *(const f4*)(xrow + 4);
    As[2] = *(const f4*)(xrow + 32);
    As[3] = *(const f4*)(xrow + 36);

    #pragma unroll
    for (int cc = 0; cc < CPW; ++cc) {
        const short* cb = wimg + (size_t)(wv * CPW + cc) * CHUNK_SH;

        // convert current A chunk -> 3-level bf16 frags
        s8 ah[2], am[2], al[2];
        const float* sv = (const float*)&As[0];
        #pragma unroll
        for (int kk = 0; kk < 2; ++kk)
            #pragma unroll
            for (int j = 0; j < 8; ++j) {
                short h, mm, l;
                split3(sv[kk * 8 + j], h, mm, l);
                ah[kk][j] = h; am[kk][j] = mm; al[kk][j] = l;
            }

        // prefetch next A chunk (latency covered by this chunk's MFMAs)
        if (cc + 1 < CPW) {
            const float* s = xrow + (cc + 1) * 64;
            As[0] = *(const f4*)(s);
            As[1] = *(const f4*)(s + 4);
            As[2] = *(const f4*)(s + 32);
            As[3] = *(const f4*)(s + 36);
        }

        #pragma unroll
        for (int kk = 0; kk < 2; ++kk) {
            // batch all 12 B-frag loads (48 VGPRs in flight) before MFMAs
            s8 bh[4], bm[4], bl[4];
            #pragma unroll
            for (int t = 0; t < 4; ++t) {
                const int pb = (kk * 3) * 256 + t * 64 + lane;
                bh[t] = *(const s8*)(cb + (size_t)(pb      ) * 8);
                bm[t] = *(const s8*)(cb + (size_t)(pb + 256) * 8);
                bl[t] = *(const s8*)(cb + (size_t)(pb + 512) * 8);
            }
            #pragma unroll
            for (int t = 0; t < 4; ++t) {
                acc0[t] = __builtin_amdgcn_mfma_f32_16x16x32_bf16(ah[kk], bh[t], acc0[t], 0, 0, 0);
                acc1[t] = __builtin_amdgcn_mfma_f32_16x16x32_bf16(ah[kk], bm[t], acc1[t], 0, 0, 0);
                acc1[t] = __builtin_amdgcn_mfma_f32_16x16x32_bf16(am[kk], bh[t], acc1[t], 0, 0, 0);
                acc1[t] = __builtin_amdgcn_mfma_f32_16x16x32_bf16(ah[kk], bl[t], acc1[t], 0, 0, 0);
                acc1[t] = __builtin_amdgcn_mfma_f32_16x16x32_bf16(am[kk], bm[t], acc1[t], 0, 0, 0);
                acc1[t] = __builtin_amdgcn_mfma_f32_16x16x32_bf16(al[kk], bh[t], acc1[t], 0, 0, 0);
            }
        }
    }

    // partial exchange: C row = q*4+r (token), col = m + 16t (expert)
    #pragma unroll
    for (int t = 0; t < 4; ++t)
        #pragma unroll
        for (int r = 0; r < 4; ++r)
            red[wv][q * 4 + r][m + 16 * t] = acc0[t][r] + acc1[t][r];

    __syncthreads();

    // fused epilogue: wave wv handles tokens wv*4 .. wv*4+3; lane = expert
    const float nw = nwt[lane];
    #pragma unroll
    for (int r = 0; r < 4; ++r) {
        const int lt  = wv * 4 + r;
        const int tok = tokBase + lt;
        const float sum = (red[0][lt][lane] + red[1][lt][lane])
                        + (red[2][lt][lane] + red[3][lt][lane]);
        const float ln = fmaf(noise[(size_t)tok * NEXP + lane], nw, sum);

        // top-1 then top-2 butterfly (r3-verified, jax tie-break)
        float v1 = ln; int i1 = lane;
        #pragma unroll
        for (int off = 32; off > 0; off >>= 1) {
            const float vo = __shfl_xor(v1, off, 64);
            const int   io = __shfl_xor(i1, off, 64);
            if (bt(vo, io, v1, i1)) { v1 = vo; i1 = io; }
        }
        float v2 = (lane == i1) ? -3.4e38f : ln; int i2 = lane;
        #pragma unroll
        for (int off = 32; off > 0; off >>= 1) {
            const float vo = __shfl_xor(v2, off, 64);
            const int   io = __shfl_xor(i2, off, 64);
            if (bt(vo, io, v2, i2)) { v2 = vo; i2 = io; }
        }

        const float d   = expf(v2 - v1);
        const float inv = 1.f / (1.f + d);
        const float wgt = (lane == i1) ? inv : ((lane == i2) ? d * inv : 0.f);
        out_w[(size_t)tok * NEXP + lane] = wgt;
        if (lane == 0) {
            out_i[(size_t)tok * 2]     = (float)i1;
            out_i[(size_t)tok * 2 + 1] = (float)i2;
        }
    }
}

extern "C" void kernel_launch(void* const* d_in, const int* in_sizes, int n_in,
                              void* d_out, int out_size, void* d_ws, size_t ws_size,
                              hipStream_t stream) {
    const float* x     = (const float*)d_in[0];
    const float* gw    = (const float*)d_in[1];
    const float* nwt   = (const float*)d_in[2];
    const float* noise = (const float*)d_in[3];
    float* out_w = (float*)d_out;                        // [NTOK][64]
    float* out_i = (float*)d_out + (size_t)NTOK * NEXP;  // [NTOK][2] as float
    short* wimg  = (short*)d_ws;                         // 384 KB image

    hipLaunchKernelGGL(w_prep, dim3(32), dim3(256), 0, stream, gw, wimg);
    hipLaunchKernelGGL(moe_fused, dim3(NTOK / 16), dim3(256), 0, stream,
                       x, wimg, nwt, noise, out_w, out_i);
}